// Round 12
// baseline (85.365 us; speedup 1.0000x reference)
//
#include <hip/hip_runtime.h>
#include <hip/hip_bf16.h>

#define B_DIM 64
#define N_IN 1000000
#define N_OUT 20000
#define KMAX 64
#define GPB 16        // groups per gather block
#define COLS 256      // columns per transpose tile
#define NFULL 3906    // 3906*256 = 999,936 full tiles
#define TAILC 64      // tail columns
#define FLAG_MAGIC 1
#define FB 1250       // flag blocks: 20000*16 int4 / 256 thr
#define LSTRIDE 260   // dwords per h-row: mult of 4 (b128 align)

typedef float f32x4 __attribute__((ext_vector_type(4)));

__device__ __forceinline__ unsigned short f32_to_bf16_bits(float f) {
    __hip_bfloat16 b = __float2bfloat16(f);
    unsigned short s;
    __builtin_memcpy(&s, &b, sizeof(s));
    return s;
}
__device__ __forceinline__ unsigned int pack_bf16x2(float lo, float hi) {
    return (unsigned int)f32_to_bf16_bits(lo) | ((unsigned int)f32_to_bf16_bits(hi) << 16);
}
__device__ __forceinline__ float bf16_lo(unsigned int u) { return __uint_as_float(u << 16); }
__device__ __forceinline__ float bf16_hi(unsigned int u) { return __uint_as_float(u & 0xFFFF0000u); }

// ---------- prep: mark used rows of x (flags only) ----------
__global__ __launch_bounds__(256) void prep_flags(
    const int* __restrict__ gidx, const int* __restrict__ lengths,
    unsigned char* __restrict__ flags) {
    int tid = blockIdx.x * 256 + threadIdx.x;   // one int4 = 4 k's
    int g  = tid >> 4;
    int k4 = (tid & 15) * 4;
    int len = lengths[g];
    int4 v = *reinterpret_cast<const int4*>(&gidx[g * KMAX + k4]);
    if (k4 + 0 < len) flags[v.x] = FLAG_MAGIC;
    if (k4 + 1 < len) flags[v.y] = FLAG_MAGIC;
    if (k4 + 2 < len) flags[v.z] = FLAG_MAGIC;
    if (k4 + 3 < len) flags[v.w] = FLAG_MAGIC;
    if (tid == 0) flags[0] = FLAG_MAGIC;        // k>=len lanes gather row 0 (weight 0)
}

// ---------- transpose + downcast + masked write: x f32(64,N_IN) -> xT bf16(N_IN,64) ----------
// LDS layout [h][c] (h = row-pair 0..31, c = col 0..255), stride 260 dwords.
// Phase 1: plain (no nt) f32x4 reads, one aligned ds_write_b128 per thread-iter.
// Phase 2: 4x b32 reads + 16B global stores, per-row usage mask.
__global__ __launch_bounds__(512) void transpose_x(
    const float* __restrict__ src, __hip_bfloat16* __restrict__ dst,
    const unsigned char* __restrict__ flags) {
    __shared__ unsigned int lt32[32 * LSTRIDE];   // 33,280 B
    __shared__ unsigned char f[COLS];
    const int t  = threadIdx.x;
    const bool full = blockIdx.x < NFULL;
    const size_t c0 = (size_t)blockIdx.x * COLS;
    const int CN = full ? COLS : TAILC;
    if (t < CN) f[t] = flags[c0 + t];
    if (full) {
        const int w = t >> 6;          // wave 0..7
        const int a = t & 63;          // lane -> cols 4a..4a+3
#pragma unroll
        for (int i = 0; i < 4; ++i) {
            int r0 = i * 16 + w * 2;   // row pair
            f32x4 v0 = *reinterpret_cast<const f32x4*>(&src[(size_t)r0 * N_IN + c0 + a * 4]);
            f32x4 v1 = *reinterpret_cast<const f32x4*>(&src[(size_t)(r0 + 1) * N_IN + c0 + a * 4]);
            int h = r0 >> 1;           // i*8 + w, distinct in 0..31
            uint4 pk;
            pk.x = pack_bf16x2(v0.x, v1.x);
            pk.y = pack_bf16x2(v0.y, v1.y);
            pk.z = pack_bf16x2(v0.z, v1.z);
            pk.w = pack_bf16x2(v0.w, v1.w);
            *reinterpret_cast<uint4*>(&lt32[h * LSTRIDE + 4 * a]) = pk;  // aligned b128
        }
    } else if (t < 256) {
        const int c = t & 63;
        const int rp = t >> 6;         // 0..3
#pragma unroll
        for (int i = 0; i < 8; ++i) {
            int r0 = i * 8 + rp * 2;
            float x0 = src[(size_t)r0 * N_IN + c0 + c];
            float x1 = src[(size_t)(r0 + 1) * N_IN + c0 + c];
            lt32[(r0 >> 1) * LSTRIDE + c] = pack_bf16x2(x0, x1);
        }
    }
    __syncthreads();
    // phase 2: xT row c = 128B = 8 lanes x 16B; lane m holds dwords 4m..4m+3
    const int m  = t & 7;              // 16B chunk
    const int cb = t >> 3;             // 0..63
#pragma unroll
    for (int i = 0; i < 4; ++i) {
        int c = cb + 64 * i;
        if (c < CN && f[c] == FLAG_MAGIC) {
            uint4 u;
            u.x = lt32[(4 * m + 0) * LSTRIDE + c];
            u.y = lt32[(4 * m + 1) * LSTRIDE + c];
            u.z = lt32[(4 * m + 2) * LSTRIDE + c];
            u.w = lt32[(4 * m + 3) * LSTRIDE + c];
            *reinterpret_cast<uint4*>(&dst[(c0 + c) * 64 + m * 8]) = u;
        }
    }
}

// ---------- gather + dot, eighth-wave, step-8 loop: ceil(len/8) 1KB gathers ----------
__global__ __launch_bounds__(1024) void gather_dot_fused(
    const __hip_bfloat16* __restrict__ xT, // (N_IN, 64) bf16
    const float* __restrict__ kern,        // (KMAX, N_OUT)
    const int*   __restrict__ gidx,        // (N_OUT, KMAX)
    const int*   __restrict__ lengths,     // (N_OUT,)
    const float* __restrict__ bias,        // (N_OUT,)
    float*       __restrict__ out) {       // (B_DIM, N_OUT)
    __shared__ float klds[GPB * 65];       // klds[c][k], stride 65
    __shared__ float sm[64 * 17];
    const int t    = threadIdx.x;
    const int wave = t >> 6;               // 0..15 -> group
    const int lane = t & 63;
    const int q = lane >> 3;               // eighth: handles k+q
    const int l = lane & 7;                // batch octet index
    const int g0 = blockIdx.x * GPB;
    const int g  = g0 + wave;

    // stage kern[0..63][g0..g0+15] -> klds
    {
        const int r = t >> 4;              // k
        const int c = t & 15;              // group in block
        klds[c * 65 + r] = kern[r * N_OUT + g0 + c];
    }
    const int len = lengths[g];
    const int idx_l = (lane < len) ? gidx[g * KMAX + lane] : 0;
    __syncthreads();
    const float w_l = (lane < len) ? klds[wave * 65 + lane] : 0.0f;

    float a0 = 0.f, a1 = 0.f, a2 = 0.f, a3 = 0.f;
    float a4 = 0.f, a5 = 0.f, a6 = 0.f, a7 = 0.f;
    for (int k = 0; k < len; k += 8) {
        int   kk  = k + q;                 // <= 63 always (k <= 56, q <= 7)
        int   row = __shfl(idx_l, kk);     // w=0, row=0 for kk >= len
        float w   = __shfl(w_l, kk);
        // eighths load 8 different rows: 8 x 128B = 1KB coalesced per instr
        uint4 uv = *reinterpret_cast<const uint4*>(&xT[(size_t)row * 64 + 8 * l]);
        a0 = fmaf(bf16_lo(uv.x), w, a0);
        a1 = fmaf(bf16_hi(uv.x), w, a1);
        a2 = fmaf(bf16_lo(uv.y), w, a2);
        a3 = fmaf(bf16_hi(uv.y), w, a3);
        a4 = fmaf(bf16_lo(uv.z), w, a4);
        a5 = fmaf(bf16_hi(uv.z), w, a5);
        a6 = fmaf(bf16_lo(uv.w), w, a6);
        a7 = fmaf(bf16_hi(uv.w), w, a7);
    }
    // reduce over q (lanes differing in bits 3..5)
#pragma unroll
    for (int s = 8; s <= 32; s <<= 1) {
        a0 += __shfl_xor(a0, s); a1 += __shfl_xor(a1, s);
        a2 += __shfl_xor(a2, s); a3 += __shfl_xor(a3, s);
        a4 += __shfl_xor(a4, s); a5 += __shfl_xor(a5, s);
        a6 += __shfl_xor(a6, s); a7 += __shfl_xor(a7, s);
    }
    if (lane < 8) {
        sm[(8 * l + 0) * 17 + wave] = a0;
        sm[(8 * l + 1) * 17 + wave] = a1;
        sm[(8 * l + 2) * 17 + wave] = a2;
        sm[(8 * l + 3) * 17 + wave] = a3;
        sm[(8 * l + 4) * 17 + wave] = a4;
        sm[(8 * l + 5) * 17 + wave] = a5;
        sm[(8 * l + 6) * 17 + wave] = a6;
        sm[(8 * l + 7) * 17 + wave] = a7;
    }
    __syncthreads();
    const int b = t >> 4;                  // 0..63
    const int c = t & 15;                  // 0..15
    __builtin_nontemporal_store(sm[b * 17 + c] + bias[g0 + c],
                                &out[(size_t)b * N_OUT + g0 + c]);
}

// ---------- fallback (ws too small): direct, slow but correct ----------
__global__ __launch_bounds__(256) void direct_kernel(
    const float* __restrict__ x, const float* __restrict__ kern,
    const float* __restrict__ bias, const int* __restrict__ gidx,
    const int* __restrict__ lengths, float* __restrict__ out) {
    const int wave = threadIdx.x >> 6;
    const int lane = threadIdx.x & 63;
    const int g = blockIdx.x * 4 + wave;
    if (g >= N_OUT) return;
    const int len = lengths[g];
    float acc = 0.0f;
    for (int k = 0; k < len; ++k) {
        int   idx = gidx[g * KMAX + k];
        float w   = kern[k * N_OUT + g];
        acc = fmaf(x[(size_t)lane * N_IN + idx], w, acc);
    }
    out[(size_t)lane * N_OUT + g] = acc + bias[g];
}

extern "C" void kernel_launch(void* const* d_in, const int* in_sizes, int n_in,
                              void* d_out, int out_size, void* d_ws, size_t ws_size,
                              hipStream_t stream) {
    const float* x       = (const float*)d_in[0];
    const float* kern    = (const float*)d_in[1];
    const float* bias    = (const float*)d_in[2];
    const int*   gidx    = (const int*)d_in[3];
    const int*   lengths = (const int*)d_in[4];
    float*       out     = (float*)d_out;

    const size_t xT_bytes = (size_t)N_IN * B_DIM * sizeof(__hip_bfloat16); // 128 MB
    const size_t fl_bytes = (size_t)N_IN;                                  // 1 MB

    if (ws_size >= xT_bytes + fl_bytes) {
        __hip_bfloat16* xT    = (__hip_bfloat16*)d_ws;
        unsigned char*  flags = (unsigned char*)((char*)d_ws + xT_bytes);

        prep_flags<<<FB, 256, 0, stream>>>(gidx, lengths, flags);
        transpose_x<<<NFULL + 1, 512, 0, stream>>>(x, xT, flags);
        gather_dot_fused<<<N_OUT / GPB, 1024, 0, stream>>>(
            xT, kern, gidx, lengths, bias, out);
    } else {
        direct_kernel<<<N_OUT / 4, 256, 0, stream>>>(x, kern, bias, gidx, lengths, out);
    }
}

// Round 13
// 83.831 us; speedup vs baseline: 1.0183x; 1.0183x over previous
//
#include <hip/hip_runtime.h>
#include <hip/hip_bf16.h>

#define B_DIM 64
#define N_IN 1000000
#define N_OUT 20000
#define KMAX 64
#define GPB 16        // groups per gather block
#define COLS 256      // columns per transpose tile
#define NFULL 3906    // 3906*256 = 999,936 full tiles
#define TAILC 64      // tail columns
#define FLAG_MAGIC 1
#define FB 1250       // flag blocks: 20000*16 int4 / 256 thr
#define LSTRIDE 260   // dwords per h-row: mult of 4 (b128 align)

typedef float f32x4 __attribute__((ext_vector_type(4)));

__device__ __forceinline__ unsigned short f32_to_bf16_bits(float f) {
    __hip_bfloat16 b = __float2bfloat16(f);
    unsigned short s;
    __builtin_memcpy(&s, &b, sizeof(s));
    return s;
}
__device__ __forceinline__ unsigned int pack_bf16x2(float lo, float hi) {
    return (unsigned int)f32_to_bf16_bits(lo) | ((unsigned int)f32_to_bf16_bits(hi) << 16);
}
__device__ __forceinline__ float bf16_lo(unsigned int u) { return __uint_as_float(u << 16); }
__device__ __forceinline__ float bf16_hi(unsigned int u) { return __uint_as_float(u & 0xFFFF0000u); }

// ---------- prep: mark used rows of x (flags only) ----------
__global__ __launch_bounds__(256) void prep_flags(
    const int* __restrict__ gidx, const int* __restrict__ lengths,
    unsigned char* __restrict__ flags) {
    int tid = blockIdx.x * 256 + threadIdx.x;   // one int4 = 4 k's
    int g  = tid >> 4;
    int k4 = (tid & 15) * 4;
    int len = lengths[g];
    int4 v = *reinterpret_cast<const int4*>(&gidx[g * KMAX + k4]);
    if (k4 + 0 < len) flags[v.x] = FLAG_MAGIC;
    if (k4 + 1 < len) flags[v.y] = FLAG_MAGIC;
    if (k4 + 2 < len) flags[v.z] = FLAG_MAGIC;
    if (k4 + 3 < len) flags[v.w] = FLAG_MAGIC;
    if (tid == 0) flags[0] = FLAG_MAGIC;        // k>=len lanes gather row 0 (weight 0)
}

// ---------- transpose + downcast + masked write: x f32(64,N_IN) -> xT bf16(N_IN,64) ----------
// LDS layout [h][c] (h = row-pair 0..31, c = col 0..255), stride 260 dwords.
// Phase 1: nt f32x4 reads (x is read-once), one aligned ds_write_b128 per thread-iter.
// Phase 2: 4x b32 reads + 16B global stores, per-row usage mask.
__global__ __launch_bounds__(512) void transpose_x(
    const float* __restrict__ src, __hip_bfloat16* __restrict__ dst,
    const unsigned char* __restrict__ flags) {
    __shared__ unsigned int lt32[32 * LSTRIDE];   // 33,280 B
    __shared__ unsigned char f[COLS];
    const int t  = threadIdx.x;
    const bool full = blockIdx.x < NFULL;
    const size_t c0 = (size_t)blockIdx.x * COLS;
    const int CN = full ? COLS : TAILC;
    if (t < CN) f[t] = flags[c0 + t];
    if (full) {
        const int w = t >> 6;          // wave 0..7
        const int a = t & 63;          // lane -> cols 4a..4a+3
#pragma unroll
        for (int i = 0; i < 4; ++i) {
            int r0 = i * 16 + w * 2;   // row pair
            f32x4 v0 = __builtin_nontemporal_load(
                reinterpret_cast<const f32x4*>(&src[(size_t)r0 * N_IN + c0 + a * 4]));
            f32x4 v1 = __builtin_nontemporal_load(
                reinterpret_cast<const f32x4*>(&src[(size_t)(r0 + 1) * N_IN + c0 + a * 4]));
            int h = r0 >> 1;           // i*8 + w, distinct in 0..31
            uint4 pk;
            pk.x = pack_bf16x2(v0.x, v1.x);
            pk.y = pack_bf16x2(v0.y, v1.y);
            pk.z = pack_bf16x2(v0.z, v1.z);
            pk.w = pack_bf16x2(v0.w, v1.w);
            *reinterpret_cast<uint4*>(&lt32[h * LSTRIDE + 4 * a]) = pk;  // aligned b128
        }
    } else if (t < 256) {
        const int c = t & 63;
        const int rp = t >> 6;         // 0..3
#pragma unroll
        for (int i = 0; i < 8; ++i) {
            int r0 = i * 8 + rp * 2;
            float x0 = src[(size_t)r0 * N_IN + c0 + c];
            float x1 = src[(size_t)(r0 + 1) * N_IN + c0 + c];
            lt32[(r0 >> 1) * LSTRIDE + c] = pack_bf16x2(x0, x1);
        }
    }
    __syncthreads();
    // phase 2: xT row c = 128B = 8 lanes x 16B; lane m holds dwords 4m..4m+3
    const int m  = t & 7;              // 16B chunk
    const int cb = t >> 3;             // 0..63
#pragma unroll
    for (int i = 0; i < 4; ++i) {
        int c = cb + 64 * i;
        if (c < CN && f[c] == FLAG_MAGIC) {
            uint4 u;
            u.x = lt32[(4 * m + 0) * LSTRIDE + c];
            u.y = lt32[(4 * m + 1) * LSTRIDE + c];
            u.z = lt32[(4 * m + 2) * LSTRIDE + c];
            u.w = lt32[(4 * m + 3) * LSTRIDE + c];
            *reinterpret_cast<uint4*>(&dst[(c0 + c) * 64 + m * 8]) = u;
        }
    }
}

// ---------- gather + dot, eighth-wave, 4-deep unroll: 4x 1KB gathers in flight ----------
__global__ __launch_bounds__(1024) void gather_dot_fused(
    const __hip_bfloat16* __restrict__ xT, // (N_IN, 64) bf16
    const float* __restrict__ kern,        // (KMAX, N_OUT)
    const int*   __restrict__ gidx,        // (N_OUT, KMAX)
    const int*   __restrict__ lengths,     // (N_OUT,)
    const float* __restrict__ bias,        // (N_OUT,)
    float*       __restrict__ out) {       // (B_DIM, N_OUT)
    __shared__ float klds[GPB * 65];       // klds[c][k], stride 65
    __shared__ float sm[64 * 17];
    const int t    = threadIdx.x;
    const int wave = t >> 6;               // 0..15 -> group
    const int lane = t & 63;
    const int q = lane >> 3;               // eighth: handles k+q
    const int l = lane & 7;                // batch octet index
    const int g0 = blockIdx.x * GPB;
    const int g  = g0 + wave;

    // stage kern[0..63][g0..g0+15] -> klds
    {
        const int r = t >> 4;              // k
        const int c = t & 15;              // group in block
        klds[c * 65 + r] = kern[r * N_OUT + g0 + c];
    }
    const int len = lengths[g];
    const int idx_l = (lane < len) ? gidx[g * KMAX + lane] : 0;
    __syncthreads();
    const float w_l = (lane < len) ? klds[wave * 65 + lane] : 0.0f;

    float a0 = 0.f, a1 = 0.f, a2 = 0.f, a3 = 0.f;
    float a4 = 0.f, a5 = 0.f, a6 = 0.f, a7 = 0.f;
    for (int k = 0; k < len; k += 32) {
#pragma unroll
        for (int j = 0; j < 4; ++j) {
            int   kk  = k + 8 * j + q;                  // <= 63 always
            int   row = __shfl(idx_l, kk);              // w=0, row=0 for kk >= len
            float w   = __shfl(w_l, kk);
            // eighths load 8 different rows: 8 x 128B = 1KB coalesced per instr
            uint4 uv = *reinterpret_cast<const uint4*>(&xT[(size_t)row * 64 + 8 * l]);
            a0 = fmaf(bf16_lo(uv.x), w, a0);
            a1 = fmaf(bf16_hi(uv.x), w, a1);
            a2 = fmaf(bf16_lo(uv.y), w, a2);
            a3 = fmaf(bf16_hi(uv.y), w, a3);
            a4 = fmaf(bf16_lo(uv.z), w, a4);
            a5 = fmaf(bf16_hi(uv.z), w, a5);
            a6 = fmaf(bf16_lo(uv.w), w, a6);
            a7 = fmaf(bf16_hi(uv.w), w, a7);
        }
    }
    // reduce over q (lanes differing in bits 3..5)
#pragma unroll
    for (int s = 8; s <= 32; s <<= 1) {
        a0 += __shfl_xor(a0, s); a1 += __shfl_xor(a1, s);
        a2 += __shfl_xor(a2, s); a3 += __shfl_xor(a3, s);
        a4 += __shfl_xor(a4, s); a5 += __shfl_xor(a5, s);
        a6 += __shfl_xor(a6, s); a7 += __shfl_xor(a7, s);
    }
    if (lane < 8) {
        sm[(8 * l + 0) * 17 + wave] = a0;
        sm[(8 * l + 1) * 17 + wave] = a1;
        sm[(8 * l + 2) * 17 + wave] = a2;
        sm[(8 * l + 3) * 17 + wave] = a3;
        sm[(8 * l + 4) * 17 + wave] = a4;
        sm[(8 * l + 5) * 17 + wave] = a5;
        sm[(8 * l + 6) * 17 + wave] = a6;
        sm[(8 * l + 7) * 17 + wave] = a7;
    }
    __syncthreads();
    const int b = t >> 4;                  // 0..63
    const int c = t & 15;                  // 0..15
    __builtin_nontemporal_store(sm[b * 17 + c] + bias[g0 + c],
                                &out[(size_t)b * N_OUT + g0 + c]);
}

// ---------- fallback (ws too small): direct, slow but correct ----------
__global__ __launch_bounds__(256) void direct_kernel(
    const float* __restrict__ x, const float* __restrict__ kern,
    const float* __restrict__ bias, const int* __restrict__ gidx,
    const int* __restrict__ lengths, float* __restrict__ out) {
    const int wave = threadIdx.x >> 6;
    const int lane = threadIdx.x & 63;
    const int g = blockIdx.x * 4 + wave;
    if (g >= N_OUT) return;
    const int len = lengths[g];
    float acc = 0.0f;
    for (int k = 0; k < len; ++k) {
        int   idx = gidx[g * KMAX + k];
        float w   = kern[k * N_OUT + g];
        acc = fmaf(x[(size_t)lane * N_IN + idx], w, acc);
    }
    out[(size_t)lane * N_OUT + g] = acc + bias[g];
}

extern "C" void kernel_launch(void* const* d_in, const int* in_sizes, int n_in,
                              void* d_out, int out_size, void* d_ws, size_t ws_size,
                              hipStream_t stream) {
    const float* x       = (const float*)d_in[0];
    const float* kern    = (const float*)d_in[1];
    const float* bias    = (const float*)d_in[2];
    const int*   gidx    = (const int*)d_in[3];
    const int*   lengths = (const int*)d_in[4];
    float*       out     = (float*)d_out;

    const size_t xT_bytes = (size_t)N_IN * B_DIM * sizeof(__hip_bfloat16); // 128 MB
    const size_t fl_bytes = (size_t)N_IN;                                  // 1 MB

    if (ws_size >= xT_bytes + fl_bytes) {
        __hip_bfloat16* xT    = (__hip_bfloat16*)d_ws;
        unsigned char*  flags = (unsigned char*)((char*)d_ws + xT_bytes);

        prep_flags<<<FB, 256, 0, stream>>>(gidx, lengths, flags);
        transpose_x<<<NFULL + 1, 512, 0, stream>>>(x, xT, flags);
        gather_dot_fused<<<N_OUT / GPB, 1024, 0, stream>>>(
            xT, kern, gidx, lengths, bias, out);
    } else {
        direct_kernel<<<N_OUT / 4, 256, 0, stream>>>(x, kern, bias, gidx, lengths, out);
    }
}